// Round 8
// baseline (312.982 us; speedup 1.0000x reference)
//
#include <hip/hip_runtime.h>
#include <hip/hip_bf16.h>

// MHA: B=4 L=2048 D=1024 H=16 DH=64, causal. Inputs f32 (sniffed; dtype-proof).
// Round 8: paired q-tiles (qt=p & 31-p, perfect load balance, 33 tiles/block),
// O^T PV orientation (per-lane scalar alpha/l, no shuffles, b64 stores),
// exp2-domain softmax (log2e folded into Q-GEMM scale). Swizzled LDS (R6).

typedef __bf16 bf16;
typedef __bf16 bf16x4 __attribute__((ext_vector_type(4)));
typedef __bf16 bf16x8 __attribute__((ext_vector_type(8)));
typedef float f32x4 __attribute__((ext_vector_type(4)));

#define DEV static __device__ __forceinline__

constexpr int B = 4, L = 2048, D = 1024, H = 16, DH = 64;
constexpr int BL = B * L;                      // 8192
constexpr int GM = 8192, GK = 1024;
constexpr int BKg = 64;                        // GEMM K-tile
constexpr int PST = 72;                        // padded P row stride (elements)

typedef __attribute__((address_space(1))) const void* gptr1;
typedef __attribute__((address_space(3))) void* lptr3;

DEV void load_lds16(const bf16* g, bf16* l) {
  __builtin_amdgcn_global_load_lds((gptr1)g, (lptr3)l, 16, 0, 0);
}

DEV f32x4 mfma(bf16x8 a, bf16x8 b, f32x4 c) {
  return __builtin_amdgcn_mfma_f32_16x16x32_bf16(a, b, c, 0, 0, 0);
}

DEV float scrub(float v) { return (v == v) ? v : 0.f; }

// ---------- dtype sniff (flag=1: bf16 storage, 0: f32) ----------
__global__ void sniff_k(const unsigned short* __restrict__ xr, int* flag) {
  __shared__ int cnt;
  if (threadIdx.x == 0) cnt = 0;
  __syncthreads();
  int local = 0;
  for (int i = threadIdx.x; i < 4096; i += 64) {
    const unsigned short u = xr[2 * i];
    const int e = (u >> 7) & 0xFF;
    if (e >= 0x70 && e <= 0x85) local++;
  }
  atomicAdd(&cnt, local);
  __syncthreads();
  if (threadIdx.x == 0) *flag = (cnt > 2048) ? 1 : 0;
}

// ---------- canonicalize x -> bf16 ----------
__global__ __launch_bounds__(256) void cvt_x_k(const void* __restrict__ src,
                                               bf16* __restrict__ dst,
                                               const int* __restrict__ flag, int n) {
  const bool isbf = (*flag != 0);
  const int stride = gridDim.x * blockDim.x * 8;
  for (int idx = (blockIdx.x * blockDim.x + threadIdx.x) * 8; idx < n; idx += stride) {
    bf16x8 o;
    if (isbf) {
      bf16x8 v = *(const bf16x8*)((const bf16*)src + idx);
      #pragma unroll
      for (int j = 0; j < 8; ++j) o[j] = (bf16)scrub((float)v[j]);
    } else {
      const float* s = (const float*)src + idx;
      #pragma unroll
      for (int j = 0; j < 8; ++j) o[j] = (bf16)scrub(s[j]);
    }
    *(bf16x8*)&dst[idx] = o;
  }
}

// ---------- 4-way transpose+canonicalize: dstz[n][k] = srcz[k][n] ----------
__global__ __launch_bounds__(256) void wtrans_cvt4_k(const void* __restrict__ W0,
                                                     const void* __restrict__ W1,
                                                     const void* __restrict__ W2,
                                                     const void* __restrict__ W3,
                                                     bf16* __restrict__ dstBase,
                                                     const int* __restrict__ flag) {
  __shared__ bf16 t[32][33];
  const bool isbf = (*flag != 0);
  const int z = blockIdx.z;
  const void* src = (z == 0) ? W0 : (z == 1) ? W1 : (z == 2) ? W2 : W3;
  bf16* dst = dstBase + (size_t)z * D * D;
  const int bx = blockIdx.x * 32, by = blockIdx.y * 32;
  const int tx = threadIdx.x & 31, ty = threadIdx.x >> 5;
  for (int i = ty; i < 32; i += 8) {
    const size_t off = (size_t)(by + i) * D + bx + tx;
    const float v = isbf ? (float)((const bf16*)src)[off] : ((const float*)src)[off];
    t[i][tx] = (bf16)scrub(v);
  }
  __syncthreads();
  for (int i = ty; i < 32; i += 8)
    dst[(size_t)(bx + i) * D + by + tx] = t[tx][i];
}

// ---------- per-head V transpose: VT[bh][d][l] = V[(b,l)][h*64+d] ----------
__global__ __launch_bounds__(256) void vtrans_k(const bf16* __restrict__ V,
                                                bf16* __restrict__ VT) {
  __shared__ __align__(16) bf16 t[64 * 72];
  const int l0 = blockIdx.x * 64, bh = blockIdx.y;
  const int b = bh >> 4, h = bh & 15;
  const int tid = threadIdx.x;
  #pragma unroll
  for (int i = 0; i < 2; ++i) {
    const int o = tid * 8 + i * 2048;
    const int lrow = o >> 6, dcol = o & 63;
    *(bf16x8*)&t[lrow * 72 + dcol] =
        *(const bf16x8*)&V[(size_t)(b * L + l0 + lrow) * D + h * 64 + dcol];
  }
  __syncthreads();
  const int d = tid >> 2, lg = (tid & 3) * 16;
  bf16x8 o0, o1;
  #pragma unroll
  for (int j = 0; j < 8; ++j) o0[j] = t[(lg + j) * 72 + d];
  #pragma unroll
  for (int j = 0; j < 8; ++j) o1[j] = t[(lg + 8 + j) * 72 + d];
  bf16* dst = VT + ((size_t)bh * DH + d) * L + l0 + lg;
  *(bf16x8*)dst = o0;
  *(bf16x8*)(dst + 8) = o1;
}

// ---------- fused QKV GEMM: [Q|K|V] = x @ [WqT|WkT|WvT]^T + b ----------
// Q epilogue folds 1/sqrt(DH) * log2(e) (exp2-domain softmax downstream).
__global__ __launch_bounds__(256) void qkv_gemm_k(const bf16* __restrict__ A,
                                                  const bf16* __restrict__ Bt,
                                                  const void* __restrict__ bq,
                                                  const void* __restrict__ bk,
                                                  const void* __restrict__ bv,
                                                  bf16* __restrict__ Q,
                                                  bf16* __restrict__ Kk,
                                                  bf16* __restrict__ V,
                                                  const int* __restrict__ flag) {
  __shared__ __align__(16) bf16 As[128 * BKg];
  __shared__ __align__(16) bf16 Bs[128 * BKg];
  const bool isbf = (*flag != 0);
  const int m0 = blockIdx.x * 128, n0 = blockIdx.y * 128;
  const int buf = n0 >> 10, nloc = n0 & 1023;
  bf16* Cb = (buf == 0) ? Q : (buf == 1) ? Kk : V;
  const void* bias = (buf == 0) ? bq : (buf == 1) ? bk : bv;
  const float scale = (buf == 0) ? 0.125f * 1.44269504088896f : 1.0f;

  const int tid = threadIdx.x, wave = tid >> 6, lane = tid & 63;
  const int wr = wave >> 1, wc = wave & 1;
  const int quad = lane >> 4, l16 = lane & 15;
  const int srow = lane >> 3;
  const int scol = ((lane ^ srow) & 7) * 8;
  const int l7 = l16 & 7;
  const int s0 = ((quad ^ l7) * 8);
  const int s1 = s0 ^ 32;

  f32x4 acc[4][4] = {};

  for (int k0 = 0; k0 < GK; k0 += BKg) {
    for (int c = wave; c < 16; c += 4) {
      load_lds16(A  + (size_t)(m0 + c * 8 + srow) * GK + k0 + scol, &As[c * 512]);
      load_lds16(Bt + (size_t)(n0 + c * 8 + srow) * GK + k0 + scol, &Bs[c * 512]);
    }
    __syncthreads();
    #pragma unroll
    for (int kk = 0; kk < BKg; kk += 32) {
      const int sk = kk ? s1 : s0;
      bf16x8 af[4], bfr[4];
      #pragma unroll
      for (int i = 0; i < 4; ++i)
        af[i] = *(const bf16x8*)&As[(wr * 64 + i * 16 + l16) * BKg + sk];
      #pragma unroll
      for (int i = 0; i < 4; ++i)
        bfr[i] = *(const bf16x8*)&Bs[(wc * 64 + i * 16 + l16) * BKg + sk];
      #pragma unroll
      for (int mi = 0; mi < 4; ++mi)
        #pragma unroll
        for (int ni = 0; ni < 4; ++ni)
          acc[mi][ni] = mfma(af[mi], bfr[ni], acc[mi][ni]);
    }
    __syncthreads();
  }

  #pragma unroll
  for (int ni = 0; ni < 4; ++ni) {
    const int col = nloc + wc * 64 + ni * 16 + l16;
    const float bv2 = isbf ? (float)((const bf16*)bias)[col] : ((const float*)bias)[col];
    #pragma unroll
    for (int mi = 0; mi < 4; ++mi)
      #pragma unroll
      for (int r = 0; r < 4; ++r) {
        const int row = m0 + wr * 64 + mi * 16 + quad * 4 + r;
        Cb[(size_t)row * D + col] = (bf16)((acc[mi][ni][r] + bv2) * scale);
      }
  }
}

// ---------- final GEMM: out = attnO @ WoT^T + bo (dtype per flag) ----------
__global__ __launch_bounds__(256) void gemm_bt_k(const bf16* __restrict__ A,
                                                 const bf16* __restrict__ Bt,
                                                 const void* __restrict__ bias,
                                                 void* __restrict__ C,
                                                 const int* __restrict__ flag) {
  __shared__ __align__(16) bf16 As[128 * BKg];
  __shared__ __align__(16) bf16 Bs[128 * BKg];
  const bool isbf = (*flag != 0);
  const int m0 = blockIdx.x * 128, n0 = blockIdx.y * 128;
  const int tid = threadIdx.x, wave = tid >> 6, lane = tid & 63;
  const int wr = wave >> 1, wc = wave & 1;
  const int quad = lane >> 4, l16 = lane & 15;
  const int srow = lane >> 3;
  const int scol = ((lane ^ srow) & 7) * 8;
  const int l7 = l16 & 7;
  const int s0 = ((quad ^ l7) * 8);
  const int s1 = s0 ^ 32;

  f32x4 acc[4][4] = {};

  for (int k0 = 0; k0 < GK; k0 += BKg) {
    for (int c = wave; c < 16; c += 4) {
      load_lds16(A  + (size_t)(m0 + c * 8 + srow) * GK + k0 + scol, &As[c * 512]);
      load_lds16(Bt + (size_t)(n0 + c * 8 + srow) * GK + k0 + scol, &Bs[c * 512]);
    }
    __syncthreads();
    #pragma unroll
    for (int kk = 0; kk < BKg; kk += 32) {
      const int sk = kk ? s1 : s0;
      bf16x8 af[4], bfr[4];
      #pragma unroll
      for (int i = 0; i < 4; ++i)
        af[i] = *(const bf16x8*)&As[(wr * 64 + i * 16 + l16) * BKg + sk];
      #pragma unroll
      for (int i = 0; i < 4; ++i)
        bfr[i] = *(const bf16x8*)&Bs[(wc * 64 + i * 16 + l16) * BKg + sk];
      #pragma unroll
      for (int mi = 0; mi < 4; ++mi)
        #pragma unroll
        for (int ni = 0; ni < 4; ++ni)
          acc[mi][ni] = mfma(af[mi], bfr[ni], acc[mi][ni]);
    }
    __syncthreads();
  }

  bf16* Cb = (bf16*)C;
  float* Cf = (float*)C;
  #pragma unroll
  for (int ni = 0; ni < 4; ++ni) {
    const int col = n0 + wc * 64 + ni * 16 + l16;
    const float bv = isbf ? (float)((const bf16*)bias)[col] : ((const float*)bias)[col];
    #pragma unroll
    for (int mi = 0; mi < 4; ++mi)
      #pragma unroll
      for (int r = 0; r < 4; ++r) {
        const int row = m0 + wr * 64 + mi * 16 + quad * 4 + r;
        const float v = acc[mi][ni][r] + bv;
        if (isbf) Cb[(size_t)row * D + col] = (bf16)v;
        else      Cf[(size_t)row * D + col] = v;
      }
  }
}

// ---------- fused causal flash attention v5 ----------
// Grid: 16 pairs x 64 bh. Block handles qt=p and qt=31-p (33 tiles each,
// perfect balance). S^T = K@Q^T; softmax per-lane scalar (q=l16), exp2
// domain (Q pre-scaled by GEMM). PV computes O^T = V@P^T so alpha & 1/l are
// per-lane scalars (no cross-lane redistribution).
__global__ __launch_bounds__(256) void attn_k(bf16* QO,
                                              const bf16* __restrict__ K,
                                              const bf16* __restrict__ VT) {
  __shared__ __align__(16) bf16 Ks[64 * DH];       // swizzled [key][d]
  __shared__ __align__(16) bf16 Vt[DH * 64];       // swizzled [d][key]
  __shared__ __align__(16) bf16 Ps[4][16 * PST];   // per-wave P^T [q][key]

  const int bx = blockIdx.x;
  const int pair = bx >> 6;
  const int bh = bx & 63;
  const int b = bh >> 4, h = bh & 15;
  const int tid = threadIdx.x, wave = tid >> 6, lane = tid & 63;
  const int quad = lane >> 4, l16 = lane & 15;
  const int srow = lane >> 3;
  const int scol = ((lane ^ srow) & 7) * 8;
  const int l7 = l16 & 7;
  const int s0 = ((quad ^ l7) * 8);
  const int s1 = s0 ^ 32;

  bf16* Qb = QO + (size_t)b * L * D + h * DH;
  const bf16* Kb = K + (size_t)b * L * D + h * DH;
  const bf16* VTg = VT + (size_t)bh * DH * L;

  for (int half = 0; half < 2; ++half) {
    const int qt = half ? (L / 64 - 1 - pair) : pair;

    // Q B-frags (scale*log2e folded in by GEMM)
    const int qrow = qt * 64 + wave * 16 + l16;
    const bf16x8 qf0 = *(const bf16x8*)(Qb + (size_t)qrow * D + quad * 8);
    const bf16x8 qf1 = *(const bf16x8*)(Qb + (size_t)qrow * D + 32 + quad * 8);

    float m_run = -INFINITY, l_run = 0.f;  // per-lane: q-row = l16
    f32x4 o_acc[4] = {};                   // O^T: row=d=quad*4+r(+db*16), col=q=l16

    for (int kt = 0; kt <= qt; ++kt) {
      for (int c = wave; c < 8; c += 4) {
        load_lds16(Kb  + (size_t)(kt * 64 + c * 8 + srow) * D + scol, &Ks[c * 512]);
        load_lds16(VTg + (size_t)(c * 8 + srow) * L + kt * 64 + scol, &Vt[c * 512]);
      }
      __syncthreads();

      // S^T = K @ Q^T: s[nb][r] = S[key=nb*16+quad*4+r][q=l16] (log2 domain)
      f32x4 s[4];
      #pragma unroll
      for (int nb = 0; nb < 4; ++nb) {
        bf16x8 k0 = *(const bf16x8*)&Ks[(nb * 16 + l16) * DH + s0];
        bf16x8 k1 = *(const bf16x8*)&Ks[(nb * 16 + l16) * DH + s1];
        f32x4 a = {};
        a = mfma(k0, qf0, a);
        a = mfma(k1, qf1, a);
        s[nb] = a;
      }

      if (kt == qt) { // diagonal causal mask
        const int qloc = wave * 16 + l16;
        #pragma unroll
        for (int nb = 0; nb < 4; ++nb)
          #pragma unroll
          for (int r = 0; r < 4; ++r)
            if (nb * 16 + quad * 4 + r > qloc) s[nb][r] = -1e30f;
      }

      // online softmax (exp2 domain), per-lane scalar state
      float mx = -INFINITY;
      #pragma unroll
      for (int nb = 0; nb < 4; ++nb)
        #pragma unroll
        for (int r = 0; r < 4; ++r) mx = fmaxf(mx, s[nb][r]);
      mx = fmaxf(mx, __shfl_xor(mx, 16, 64));
      mx = fmaxf(mx, __shfl_xor(mx, 32, 64));
      const float mn = fmaxf(m_run, mx);
      const float alpha = exp2f(m_run - mn);
      m_run = mn;

      bf16* Pw = &Ps[wave][0];
      float sum = 0.f;
      #pragma unroll
      for (int nb = 0; nb < 4; ++nb) {
        bf16x4 pk;
        #pragma unroll
        for (int r = 0; r < 4; ++r) {
          const float p = exp2f(s[nb][r] - mn);
          sum += p;
          pk[r] = (bf16)p;
        }
        *(bf16x4*)&Pw[l16 * PST + nb * 16 + quad * 4] = pk;
      }
      sum += __shfl_xor(sum, 16, 64);
      sum += __shfl_xor(sum, 32, 64);
      l_run = l_run * alpha + sum;

      #pragma unroll
      for (int db = 0; db < 4; ++db)
        #pragma unroll
        for (int r = 0; r < 4; ++r) o_acc[db][r] *= alpha;

      // O^T += V @ P^T (A = V^T[d][k] swizzled, B = P^T[q][k] from LDS)
      bf16x8 p0 = *(const bf16x8*)&Pw[l16 * PST + quad * 8];
      bf16x8 p1 = *(const bf16x8*)&Pw[l16 * PST + 32 + quad * 8];
      #pragma unroll
      for (int db = 0; db < 4; ++db) {
        bf16x8 v0 = *(const bf16x8*)&Vt[(db * 16 + l16) * 64 + s0];
        bf16x8 v1 = *(const bf16x8*)&Vt[(db * 16 + l16) * 64 + s1];
        o_acc[db] = mfma(v0, p0, o_acc[db]);
        o_acc[db] = mfma(v1, p1, o_acc[db]);
      }
      __syncthreads(); // protect Ks/Vt before next staging
    }

    // epilogue: lane owns q-row l16; d = db*16 + quad*4 + r (r contiguous)
    const float inv = 1.f / l_run;
    bf16* orow = Qb + (size_t)(qt * 64 + wave * 16 + l16) * D;
    #pragma unroll
    for (int db = 0; db < 4; ++db) {
      bf16x4 ov;
      #pragma unroll
      for (int r = 0; r < 4; ++r) ov[r] = (bf16)(o_acc[db][r] * inv);
      *(bf16x4*)&orow[db * 16 + quad * 4] = ov;
    }
  }
}

extern "C" void kernel_launch(void* const* d_in, const int* in_sizes, int n_in,
                              void* d_out, int out_size, void* d_ws, size_t ws_size,
                              hipStream_t stream) {
  const void* x  = d_in[0];
  const void* Wq = d_in[1];
  const void* bq = d_in[2];
  const void* Wk = d_in[3];
  const void* bk = d_in[4];
  const void* Wv = d_in[5];
  const void* bv = d_in[6];
  const void* Wo = d_in[7];
  const void* bo = d_in[8];
  // d_in[9] = causal mask, analytic

  int* flag = (int*)d_ws;
  char* p = (char*)d_ws + 4096;
  bf16* xc  = (bf16*)p;                 p += (size_t)BL * D * 2;
  bf16* WqT = (bf16*)p;                 p += (size_t)D * D * 2; // stacked WqT/WkT/WvT/WoT
  bf16* WkT = (bf16*)p;                 p += (size_t)D * D * 2;
  bf16* WvT = (bf16*)p;                 p += (size_t)D * D * 2;
  bf16* WoT = (bf16*)p;                 p += (size_t)D * D * 2;
  bf16* Qb  = (bf16*)p;                 p += (size_t)BL * D * 2; // O aliases Q
  bf16* Kb  = (bf16*)p;                 p += (size_t)BL * D * 2;
  bf16* Vb  = (bf16*)p;
  bf16* VTb = xc; // xc dead after QKV GEMM; reuse for V^T
  (void)WkT; (void)WvT;

  sniff_k<<<1, 64, 0, stream>>>((const unsigned short*)x, flag);

  cvt_x_k<<<1024, 256, 0, stream>>>(x, xc, flag, BL * D);
  wtrans_cvt4_k<<<dim3(32, 32, 4), 256, 0, stream>>>(Wq, Wk, Wv, Wo, WqT, flag);

  qkv_gemm_k<<<dim3(GM / 128, 3072 / 128), 256, 0, stream>>>(
      xc, WqT, bq, bk, bv, Qb, Kb, Vb, flag);

  vtrans_k<<<dim3(L / 64, B * H), 256, 0, stream>>>(Vb, VTb);

  attn_k<<<dim3((L / 128) * B * H), 256, 0, stream>>>(Qb, Kb, VTb);

  gemm_bt_k<<<dim3(GM / 128, D / 128), 256, 0, stream>>>(Qb, WoT, bo, d_out, flag);
}